// Round 7
// baseline (119.304 us; speedup 1.0000x reference)
//
#include <hip/hip_runtime.h>
#include <hip/hip_bf16.h>

typedef __attribute__((ext_vector_type(8))) short bf16x8;
typedef __attribute__((ext_vector_type(4))) float f32x4;

#define MFMA16(a,b,c) __builtin_amdgcn_mfma_f32_16x16x32_bf16((a),(b),(c),0,0,0)

static __device__ __forceinline__ unsigned short f2bf(float f) {
    unsigned int u = __builtin_bit_cast(unsigned int, f);
    u += 0x7fffu + ((u >> 16) & 1u);
    return (unsigned short)(u >> 16);
}

// async global->LDS, 16B per lane. LDS dest must be wave-uniform; HW adds lane*16.
static __device__ __forceinline__ void g2l16(const unsigned short* g, unsigned short* l) {
    __builtin_amdgcn_global_load_lds(
        (const __attribute__((address_space(1))) unsigned int*)g,
        (__attribute__((address_space(3))) unsigned int*)l,
        16, 0, 0);
}

// Problem constants (B=2, T=2048, D=2048, d=1024, kv=64)
#define BT     4096
#define DFULL  2048
#define DACT   1024
#define DKV    64
#define NSEL   512
#define TSEQ   2048
#define PADR   72

// ---------------------------------------------------------------------------
// Kernel 1: xs -> bf16, selected W rows/cols -> bf16, zero-fill padded out cols
// ---------------------------------------------------------------------------
__global__ __launch_bounds__(256) void prep_kernel(
    const float* __restrict__ x,  const float* __restrict__ Wq,
    const float* __restrict__ Wk, const float* __restrict__ Wv,
    const float* __restrict__ Wo,
    unsigned short* __restrict__ xb,  unsigned short* __restrict__ Wqb,
    unsigned short* __restrict__ Wkb, unsigned short* __restrict__ Wvb,
    unsigned short* __restrict__ Wob, float* __restrict__ out)
{
    const int NA = (BT * DACT) / 8;
    const int NB = (NSEL * DACT) / 8;
    const int NC = (DACT * NSEL) / 8;
    const int ND = (BT * DACT) / 8;
    const int TOT = NA + 3 * NB + NC + ND;
    for (int u = blockIdx.x * blockDim.x + threadIdx.x; u < TOT;
         u += gridDim.x * blockDim.x) {
        if (u < NA) {
            int e = u * 8; int row = e >> 10, col = e & 1023;
            const float* s = x + (size_t)row * DFULL + col;
            f32x4 v0 = *(const f32x4*)s, v1 = *(const f32x4*)(s + 4);
            bf16x8 o;
            #pragma unroll
            for (int j = 0; j < 4; ++j) { o[j] = (short)f2bf(v0[j]); o[4+j] = (short)f2bf(v1[j]); }
            *(bf16x8*)(xb + e) = o;
        } else if (u < NA + 3 * NB) {
            int t = u - NA; int mat = t / NB; int q = t % NB;
            int e = q * 8; int n = e >> 10, c = e & 1023;
            const float* W = (mat == 0) ? Wq : (mat == 1) ? Wk : Wv;
            unsigned short* Wb = (mat == 0) ? Wqb : (mat == 1) ? Wkb : Wvb;
            int wrow = (n >> 6) * 128 + (n & 63);
            const float* s = W + (size_t)wrow * DFULL + c;
            f32x4 v0 = *(const f32x4*)s, v1 = *(const f32x4*)(s + 4);
            bf16x8 o;
            #pragma unroll
            for (int j = 0; j < 4; ++j) { o[j] = (short)f2bf(v0[j]); o[4+j] = (short)f2bf(v1[j]); }
            *(bf16x8*)(Wb + e) = o;
        } else if (u < NA + 3 * NB + NC) {
            int q = u - NA - 3 * NB;
            int e = q * 8; int r = e >> 9, cs = e & 511;
            int col = (cs >> 6) * 128 + (cs & 63);
            const float* s = Wo + (size_t)r * DFULL + col;
            f32x4 v0 = *(const f32x4*)s, v1 = *(const f32x4*)(s + 4);
            bf16x8 o;
            #pragma unroll
            for (int j = 0; j < 4; ++j) { o[j] = (short)f2bf(v0[j]); o[4+j] = (short)f2bf(v1[j]); }
            *(bf16x8*)(Wob + e) = o;
        } else {
            int q = u - (NA + 3 * NB + NC);
            int e = q * 8; int row = e >> 10, col = e & 1023;
            float* dp = out + (size_t)row * DFULL + DACT + col;
            f32x4 z = {0.f, 0.f, 0.f, 0.f};
            *(f32x4*)dp = z; *(f32x4*)(dp + 4) = z;
        }
    }
}

// ---------------------------------------------------------------------------
// Kernel 2: unified QKV GEMM  C[4096,1536] = xb[4096,1024] . Wall[1536,1024]^T
// ---------------------------------------------------------------------------
__global__ __launch_bounds__(256) void qkv_gemm(
    const unsigned short* __restrict__ xb,
    const unsigned short* __restrict__ Wall,
    unsigned short* __restrict__ Qb, unsigned short* __restrict__ Kb,
    unsigned short* __restrict__ Vb)
{
    __shared__ unsigned short As[128 * 64];
    __shared__ unsigned short Bs[128 * 64];
    const int m0 = blockIdx.x * 128, n0 = blockIdx.y * 128;
    const int tid = threadIdx.x, w = tid >> 6, l = tid & 63;
    const int lr = l & 15, g = l >> 4, lk = g * 8;
    const int wr = w >> 1, wc = w & 1;
    const int srow = l >> 3, scol = (l & 7) * 8;

    f32x4 acc[4][4] = {};
    for (int k0 = 0; k0 < DACT; k0 += 64) {
        __syncthreads();
        #pragma unroll
        for (int i = 0; i < 4; ++i) {
            int chunk = w * 4 + i;
            int row = chunk * 8 + srow;
            g2l16(&xb[(size_t)(m0 + row) * DACT + k0 + scol], &As[chunk * 512]);
            g2l16(&Wall[(size_t)(n0 + row) * DACT + k0 + scol], &Bs[chunk * 512]);
        }
        __syncthreads();
        #pragma unroll
        for (int kk = 0; kk < 64; kk += 32) {
            bf16x8 a[4], b[4];
            #pragma unroll
            for (int m = 0; m < 4; ++m)
                a[m] = *(const bf16x8*)&As[(wr * 64 + m * 16 + lr) * 64 + kk + lk];
            #pragma unroll
            for (int n = 0; n < 4; ++n)
                b[n] = *(const bf16x8*)&Bs[(wc * 64 + n * 16 + lr) * 64 + kk + lk];
            #pragma unroll
            for (int m = 0; m < 4; ++m)
                #pragma unroll
                for (int n = 0; n < 4; ++n)
                    acc[m][n] = MFMA16(a[m], b[n], acc[m][n]);
        }
    }
    #pragma unroll
    for (int m = 0; m < 4; ++m)
        #pragma unroll
        for (int n = 0; n < 4; ++n)
            #pragma unroll
            for (int i = 0; i < 4; ++i) {
                int row = m0 + wr * 64 + m * 16 + g * 4 + i;
                int col = n0 + wc * 64 + n * 16 + lr;
                int mat = col >> 9, r = col & 511, h = r >> 6, j = r & 63;
                int bb = row >> 11, t = row & 2047, bh = bb * 8 + h;
                size_t off = ((size_t)bh * TSEQ + t) * DKV + j;
                float v = acc[m][n][i];
                if (mat == 0)      Qb[off] = f2bf(v * 0.125f);
                else if (mat == 1) Kb[off] = f2bf(v);
                else               Vb[off] = f2bf(v);
            }
}

// ---------------------------------------------------------------------------
// Kernel 3: V transpose  Vb[bh][t][64] -> Vtb[bh][64][t]
// ---------------------------------------------------------------------------
__global__ __launch_bounds__(256) void vtrans_kernel(
    const unsigned short* __restrict__ Vb, unsigned short* __restrict__ Vtb)
{
    __shared__ unsigned short Ls[64 * PADR];
    const int t0 = blockIdx.x * 64, bh = blockIdx.y;
    const int tid = threadIdx.x;
    #pragma unroll
    for (int it = 0; it < 2; ++it) {
        int r = (tid >> 3) + it * 32, c = (tid & 7) * 8;
        *(bf16x8*)&Ls[r * PADR + c] =
            *(const bf16x8*)&Vb[((size_t)bh * TSEQ + t0 + r) * DKV + c];
    }
    __syncthreads();
    int dv = tid >> 2, tt0 = (tid & 3) * 16;
    unsigned short tmp[16];
    #pragma unroll
    for (int j = 0; j < 16; ++j) tmp[j] = Ls[(tt0 + j) * PADR + dv];
    size_t ob = ((size_t)bh * DKV + dv) * TSEQ + t0 + tt0;
    *(bf16x8*)&Vtb[ob]     = *(bf16x8*)&tmp[0];
    *(bf16x8*)&Vtb[ob + 8] = *(bf16x8*)&tmp[8];
}

// ---------------------------------------------------------------------------
// Kernel 4: causal attention, max-free softmax, den via ones-MFMA.
// SPLIT-K-8 (512 thr) + BATCHED FRAGMENT LOADS: all 16 K/V fragment loads
// of a visit are issued together into registers (one vmcnt wait per visit,
// ~110 VGPR) instead of 12 serialized L2 round-trips at 64 VGPR.
// Block = pair of 32-row q-tiles (Q, 63-Q); wave w takes jt = w mod 8;
// linear-sum merge in LDS per half. 512 uniform blocks, 2/CU, 4 waves/SIMD.
// XCD-bijective: blockIdx&7 = XCD, 2 bh per XCD (1MB K/V in its L2).
// ---------------------------------------------------------------------------
__global__ __launch_bounds__(512, 4) void attn_kernel(
    const unsigned short* __restrict__ Qb,
    const unsigned short* __restrict__ Kb,
    const unsigned short* __restrict__ Vtb,
    unsigned short* __restrict__ att)
{
    __shared__ __align__(16) char smem[70656];   // merge: Ns[8][32][68]f32|Ds[8][32]; loop: Ps[8][32*72]bf16 aliases
    const int f = blockIdx.x;
    const int xcd = f & 7, idx = f >> 3;         // idx in [0,64)
    const int bh = xcd * 2 + (idx >> 5);
    const int pr = idx & 31;                     // pair index
    const int tid = threadIdx.x, w = tid >> 6, l = tid & 63;
    const int lr = l & 15, g = l >> 4, lk = g * 8;
    const size_t kvb = (size_t)bh * TSEQ * DKV;
    const int bb = bh >> 3, h = bh & 7;

    unsigned short* Psw = (unsigned short*)smem + w * (32 * PADR);
    const short os = (short)0x3F80;              // bf16 1.0
    const bf16x8 ones = {os, os, os, os, os, os, os, os};

    #pragma unroll 1
    for (int half = 0; half < 2; ++half) {
        const int Q = half ? (63 - pr) : pr;
        const int q0 = Q * 32;
        const int ntiles = (Q >> 1) + 1;
        const int last = ntiles - 1;

        bf16x8 qf00 = *(const bf16x8*)&Qb[kvb + (size_t)(q0 +      lr) * DKV + lk];
        bf16x8 qf01 = *(const bf16x8*)&Qb[kvb + (size_t)(q0 +      lr) * DKV + 32 + lk];
        bf16x8 qf10 = *(const bf16x8*)&Qb[kvb + (size_t)(q0 + 16 + lr) * DKV + lk];
        bf16x8 qf11 = *(const bf16x8*)&Qb[kvb + (size_t)(q0 + 16 + lr) * DKV + 32 + lk];

        f32x4 acc0[4] = {}, acc1[4] = {};
        f32x4 dacc0 = {}, dacc1 = {};

        for (int jt = w; jt < ntiles; jt += 8) {
            const unsigned short* Kt = Kb + kvb + (size_t)jt * 64 * DKV;
            const unsigned short* Vt = Vtb + kvb + jt * 64;

            // ---- issue ALL 16 fragment loads up front (single in-flight
            //      group, one wait) ----
            bf16x8 kf0[4], kf1[4], vf0[4], vf1[4];
            #pragma unroll
            for (int c = 0; c < 4; ++c) {
                kf0[c] = *(const bf16x8*)&Kt[(c * 16 + lr) * DKV + lk];
                kf1[c] = *(const bf16x8*)&Kt[(c * 16 + lr) * DKV + 32 + lk];
            }
            #pragma unroll
            for (int n = 0; n < 4; ++n) {
                vf0[n] = *(const bf16x8*)&Vt[(size_t)(n * 16 + lr) * TSEQ + lk];
                vf1[n] = *(const bf16x8*)&Vt[(size_t)(n * 16 + lr) * TSEQ + 32 + lk];
            }

            // ---- QK^T, mask, exp, stash P to wave-private LDS ----
            #pragma unroll
            for (int c = 0; c < 4; ++c) {
                f32x4 z0 = {}, z1 = {};
                z0 = MFMA16(qf00, kf0[c], z0); z0 = MFMA16(qf01, kf1[c], z0);
                z1 = MFMA16(qf10, kf0[c], z1); z1 = MFMA16(qf11, kf1[c], z1);
                if (jt == last) {                // causal mask, diagonal tile only
                    int kcol = jt * 64 + c * 16 + lr;
                    #pragma unroll
                    for (int i = 0; i < 4; ++i) {
                        if (kcol > q0 +      g * 4 + i) z0[i] = -64.f;
                        if (kcol > q0 + 16 + g * 4 + i) z1[i] = -64.f;
                    }
                }
                #pragma unroll
                for (int i = 0; i < 4; ++i) {
                    Psw[(     g * 4 + i) * PADR + c * 16 + lr] = f2bf(__expf(z0[i]));
                    Psw[(16 + g * 4 + i) * PADR + c * 16 + lr] = f2bf(__expf(z1[i]));
                }
            }
            bf16x8 pa00 = *(const bf16x8*)&Psw[      lr  * PADR + lk];
            bf16x8 pa01 = *(const bf16x8*)&Psw[      lr  * PADR + 32 + lk];
            bf16x8 pa10 = *(const bf16x8*)&Psw[(16 + lr) * PADR + lk];
            bf16x8 pa11 = *(const bf16x8*)&Psw[(16 + lr) * PADR + 32 + lk];

            // ---- PV from pre-loaded V fragments; den via ones-MFMA ----
            #pragma unroll
            for (int n = 0; n < 4; ++n) {
                acc0[n] = MFMA16(pa00, vf0[n], acc0[n]);
                acc0[n] = MFMA16(pa01, vf1[n], acc0[n]);
                acc1[n] = MFMA16(pa10, vf0[n], acc1[n]);
                acc1[n] = MFMA16(pa11, vf1[n], acc1[n]);
            }
            dacc0 = MFMA16(pa00, ones, dacc0); dacc0 = MFMA16(pa01, ones, dacc0);
            dacc1 = MFMA16(pa10, ones, dacc1); dacc1 = MFMA16(pa11, ones, dacc1);
        }

        // ---- deterministic linear merge of the 8 per-wave partials ----
        __syncthreads();
        float* Ns = (float*)smem;                    // [8][32][68]
        float* Ds = (float*)(smem + 69632);          // [8][32]
        #pragma unroll
        for (int n = 0; n < 4; ++n)
            #pragma unroll
            for (int i = 0; i < 4; ++i) {
                Ns[(size_t)w * (32 * 68) + (     g * 4 + i) * 68 + n * 16 + lr] = acc0[n][i];
                Ns[(size_t)w * (32 * 68) + (16 + g * 4 + i) * 68 + n * 16 + lr] = acc1[n][i];
            }
        if (lr == 0) {
            #pragma unroll
            for (int i = 0; i < 4; ++i) {
                Ds[w * 32 +      g * 4 + i] = dacc0[i];
                Ds[w * 32 + 16 + g * 4 + i] = dacc1[i];
            }
        }
        __syncthreads();

        // 512 threads cover 32 rows x 64 cols, 4 cols/thread
        const int row = tid >> 4, c0 = (tid & 15) * 4;
        float den = 0.f;
        #pragma unroll
        for (int ww = 0; ww < 8; ++ww) den += Ds[ww * 32 + row];
        float inv = 1.0f / den;
        unsigned short o[4];
        #pragma unroll
        for (int j = 0; j < 4; ++j) {
            float s = 0.f;
            #pragma unroll
            for (int ww = 0; ww < 8; ++ww)
                s += Ns[(size_t)ww * (32 * 68) + row * 68 + c0 + j];
            o[j] = f2bf(s * inv);
        }
        *(unsigned long long*)&att[((size_t)bb * TSEQ + q0 + row) * NSEL + h * 64 + c0] =
            *(unsigned long long*)o;
        __syncthreads();   // protect smem before next half reuses Ps
    }
}

// ---------------------------------------------------------------------------
// Kernel 5: output projection  out[4096,1024] = att[4096,512] . Wob[1024,512]^T
// ---------------------------------------------------------------------------
__global__ __launch_bounds__(256) void oproj_gemm(
    const unsigned short* __restrict__ att,
    const unsigned short* __restrict__ Wob,
    float* __restrict__ out)
{
    __shared__ unsigned short As[128 * 64];
    __shared__ unsigned short Bs[128 * 64];
    const int m0 = blockIdx.x * 128, n0 = blockIdx.y * 128;
    const int tid = threadIdx.x, w = tid >> 6, l = tid & 63;
    const int lr = l & 15, g = l >> 4, lk = g * 8;
    const int wr = w >> 1, wc = w & 1;
    const int srow = l >> 3, scol = (l & 7) * 8;

    f32x4 acc[4][4] = {};
    for (int k0 = 0; k0 < NSEL; k0 += 64) {
        __syncthreads();
        #pragma unroll
        for (int i = 0; i < 4; ++i) {
            int chunk = w * 4 + i;
            int row = chunk * 8 + srow;
            g2l16(&att[(size_t)(m0 + row) * NSEL + k0 + scol], &As[chunk * 512]);
            g2l16(&Wob[(size_t)(n0 + row) * NSEL + k0 + scol], &Bs[chunk * 512]);
        }
        __syncthreads();
        #pragma unroll
        for (int kk = 0; kk < 64; kk += 32) {
            bf16x8 a[4], b[4];
            #pragma unroll
            for (int m = 0; m < 4; ++m)
                a[m] = *(const bf16x8*)&As[(wr * 64 + m * 16 + lr) * 64 + kk + lk];
            #pragma unroll
            for (int n = 0; n < 4; ++n)
                b[n] = *(const bf16x8*)&Bs[(wc * 64 + n * 16 + lr) * 64 + kk + lk];
            #pragma unroll
            for (int m = 0; m < 4; ++m)
                #pragma unroll
                for (int n = 0; n < 4; ++n)
                    acc[m][n] = MFMA16(a[m], b[n], acc[m][n]);
        }
    }
    #pragma unroll
    for (int m = 0; m < 4; ++m)
        #pragma unroll
        for (int n = 0; n < 4; ++n)
            #pragma unroll
            for (int i = 0; i < 4; ++i) {
                int row = m0 + wr * 64 + m * 16 + g * 4 + i;
                int col = n0 + wc * 64 + n * 16 + lr;
                out[(size_t)row * DFULL + col] = acc[m][n][i];
            }
}

// ---------------------------------------------------------------------------
extern "C" void kernel_launch(void* const* d_in, const int* in_sizes, int n_in,
                              void* d_out, int out_size, void* d_ws, size_t ws_size,
                              hipStream_t stream) {
    const float* x  = (const float*)d_in[0];
    const float* Wq = (const float*)d_in[1];
    const float* Wk = (const float*)d_in[2];
    const float* Wv = (const float*)d_in[3];
    const float* Wo = (const float*)d_in[4];
    float* out = (float*)d_out;

    char* ws = (char*)d_ws;
    unsigned short* xb  = (unsigned short*)(ws);                    // 8 MB
    unsigned short* Wqb = (unsigned short*)(ws + 8388608);          // 1 MB each,
    unsigned short* Wkb = (unsigned short*)(ws + 9437184);          // contiguous = Wall
    unsigned short* Wvb = (unsigned short*)(ws + 10485760);
    unsigned short* Wob = (unsigned short*)(ws + 11534336);         // 1 MB
    unsigned short* Qb  = (unsigned short*)(ws + 12582912);         // 4 MB
    unsigned short* Kb  = (unsigned short*)(ws + 16777216);         // 4 MB
    unsigned short* Vtb = (unsigned short*)(ws + 20971520);         // 4 MB
    unsigned short* Vb  = (unsigned short*)(ws + 25165824);         // 4 MB, dead after
    unsigned short* att = (unsigned short*)(ws + 25165824);         //   vtrans -> reuse

    prep_kernel<<<2048, 256, 0, stream>>>(x, Wq, Wk, Wv, Wo,
                                          xb, Wqb, Wkb, Wvb, Wob, out);
    qkv_gemm<<<dim3(32, 12), 256, 0, stream>>>(xb, Wqb, Qb, Kb, Vb);
    vtrans_kernel<<<dim3(32, 16), 256, 0, stream>>>(Vb, Vtb);
    attn_kernel<<<512, 512, 0, stream>>>(Qb, Kb, Vtb, att);
    oproj_gemm<<<dim3(32, 8), 256, 0, stream>>>(att, Wob, out);
}

// Round 8
// 99.755 us; speedup vs baseline: 1.1960x; 1.1960x over previous
//
#include <hip/hip_runtime.h>
#include <hip/hip_bf16.h>

typedef __attribute__((ext_vector_type(8))) short bf16x8;
typedef __attribute__((ext_vector_type(4))) float f32x4;

#define MFMA16(a,b,c) __builtin_amdgcn_mfma_f32_16x16x32_bf16((a),(b),(c),0,0,0)

static __device__ __forceinline__ unsigned short f2bf(float f) {
    unsigned int u = __builtin_bit_cast(unsigned int, f);
    u += 0x7fffu + ((u >> 16) & 1u);
    return (unsigned short)(u >> 16);
}

// async global->LDS, 16B per lane. LDS dest must be wave-uniform; HW adds lane*16.
static __device__ __forceinline__ void g2l16(const unsigned short* g, unsigned short* l) {
    __builtin_amdgcn_global_load_lds(
        (const __attribute__((address_space(1))) unsigned int*)g,
        (__attribute__((address_space(3))) unsigned int*)l,
        16, 0, 0);
}

// Problem constants (B=2, T=2048, D=2048, d=1024, kv=64)
#define BT     4096
#define DFULL  2048
#define DACT   1024
#define DKV    64
#define NSEL   512
#define TSEQ   2048
#define PADR   72

// ---------------------------------------------------------------------------
// Kernel 1: xs -> bf16, selected W rows/cols -> bf16, zero-fill padded out cols
// ---------------------------------------------------------------------------
__global__ __launch_bounds__(256) void prep_kernel(
    const float* __restrict__ x,  const float* __restrict__ Wq,
    const float* __restrict__ Wk, const float* __restrict__ Wv,
    const float* __restrict__ Wo,
    unsigned short* __restrict__ xb,  unsigned short* __restrict__ Wqb,
    unsigned short* __restrict__ Wkb, unsigned short* __restrict__ Wvb,
    unsigned short* __restrict__ Wob, float* __restrict__ out)
{
    const int NA = (BT * DACT) / 8;
    const int NB = (NSEL * DACT) / 8;
    const int NC = (DACT * NSEL) / 8;
    const int ND = (BT * DACT) / 8;
    const int TOT = NA + 3 * NB + NC + ND;
    for (int u = blockIdx.x * blockDim.x + threadIdx.x; u < TOT;
         u += gridDim.x * blockDim.x) {
        if (u < NA) {
            int e = u * 8; int row = e >> 10, col = e & 1023;
            const float* s = x + (size_t)row * DFULL + col;
            f32x4 v0 = *(const f32x4*)s, v1 = *(const f32x4*)(s + 4);
            bf16x8 o;
            #pragma unroll
            for (int j = 0; j < 4; ++j) { o[j] = (short)f2bf(v0[j]); o[4+j] = (short)f2bf(v1[j]); }
            *(bf16x8*)(xb + e) = o;
        } else if (u < NA + 3 * NB) {
            int t = u - NA; int mat = t / NB; int q = t % NB;
            int e = q * 8; int n = e >> 10, c = e & 1023;
            const float* W = (mat == 0) ? Wq : (mat == 1) ? Wk : Wv;
            unsigned short* Wb = (mat == 0) ? Wqb : (mat == 1) ? Wkb : Wvb;
            int wrow = (n >> 6) * 128 + (n & 63);
            const float* s = W + (size_t)wrow * DFULL + c;
            f32x4 v0 = *(const f32x4*)s, v1 = *(const f32x4*)(s + 4);
            bf16x8 o;
            #pragma unroll
            for (int j = 0; j < 4; ++j) { o[j] = (short)f2bf(v0[j]); o[4+j] = (short)f2bf(v1[j]); }
            *(bf16x8*)(Wb + e) = o;
        } else if (u < NA + 3 * NB + NC) {
            int q = u - NA - 3 * NB;
            int e = q * 8; int r = e >> 9, cs = e & 511;
            int col = (cs >> 6) * 128 + (cs & 63);
            const float* s = Wo + (size_t)r * DFULL + col;
            f32x4 v0 = *(const f32x4*)s, v1 = *(const f32x4*)(s + 4);
            bf16x8 o;
            #pragma unroll
            for (int j = 0; j < 4; ++j) { o[j] = (short)f2bf(v0[j]); o[4+j] = (short)f2bf(v1[j]); }
            *(bf16x8*)(Wob + e) = o;
        } else {
            int q = u - (NA + 3 * NB + NC);
            int e = q * 8; int row = e >> 10, col = e & 1023;
            float* dp = out + (size_t)row * DFULL + DACT + col;
            f32x4 z = {0.f, 0.f, 0.f, 0.f};
            *(f32x4*)dp = z; *(f32x4*)(dp + 4) = z;
        }
    }
}

// ---------------------------------------------------------------------------
// Kernel 2: unified QKV GEMM  C[4096,1536] = xb[4096,1024] . Wall[1536,1024]^T
// ---------------------------------------------------------------------------
__global__ __launch_bounds__(256) void qkv_gemm(
    const unsigned short* __restrict__ xb,
    const unsigned short* __restrict__ Wall,
    unsigned short* __restrict__ Qb, unsigned short* __restrict__ Kb,
    unsigned short* __restrict__ Vb)
{
    __shared__ unsigned short As[128 * 64];
    __shared__ unsigned short Bs[128 * 64];
    const int m0 = blockIdx.x * 128, n0 = blockIdx.y * 128;
    const int tid = threadIdx.x, w = tid >> 6, l = tid & 63;
    const int lr = l & 15, g = l >> 4, lk = g * 8;
    const int wr = w >> 1, wc = w & 1;
    const int srow = l >> 3, scol = (l & 7) * 8;

    f32x4 acc[4][4] = {};
    for (int k0 = 0; k0 < DACT; k0 += 64) {
        __syncthreads();
        #pragma unroll
        for (int i = 0; i < 4; ++i) {
            int chunk = w * 4 + i;
            int row = chunk * 8 + srow;
            g2l16(&xb[(size_t)(m0 + row) * DACT + k0 + scol], &As[chunk * 512]);
            g2l16(&Wall[(size_t)(n0 + row) * DACT + k0 + scol], &Bs[chunk * 512]);
        }
        __syncthreads();
        #pragma unroll
        for (int kk = 0; kk < 64; kk += 32) {
            bf16x8 a[4], b[4];
            #pragma unroll
            for (int m = 0; m < 4; ++m)
                a[m] = *(const bf16x8*)&As[(wr * 64 + m * 16 + lr) * 64 + kk + lk];
            #pragma unroll
            for (int n = 0; n < 4; ++n)
                b[n] = *(const bf16x8*)&Bs[(wc * 64 + n * 16 + lr) * 64 + kk + lk];
            #pragma unroll
            for (int m = 0; m < 4; ++m)
                #pragma unroll
                for (int n = 0; n < 4; ++n)
                    acc[m][n] = MFMA16(a[m], b[n], acc[m][n]);
        }
    }
    #pragma unroll
    for (int m = 0; m < 4; ++m)
        #pragma unroll
        for (int n = 0; n < 4; ++n)
            #pragma unroll
            for (int i = 0; i < 4; ++i) {
                int row = m0 + wr * 64 + m * 16 + g * 4 + i;
                int col = n0 + wc * 64 + n * 16 + lr;
                int mat = col >> 9, r = col & 511, h = r >> 6, j = r & 63;
                int bb = row >> 11, t = row & 2047, bh = bb * 8 + h;
                size_t off = ((size_t)bh * TSEQ + t) * DKV + j;
                float v = acc[m][n][i];
                if (mat == 0)      Qb[off] = f2bf(v * 0.125f);
                else if (mat == 1) Kb[off] = f2bf(v);
                else               Vb[off] = f2bf(v);
            }
}

// ---------------------------------------------------------------------------
// Kernel 3: V transpose  Vb[bh][t][64] -> TILED V^T: Vtb[bh][t/64][j][t%64]
// (64x64 contiguous tiles so attn's PV fragment loads are 128B/lane stride,
//  not 4KB — the 4KB stride was serializing in L2.)
// ---------------------------------------------------------------------------
__global__ __launch_bounds__(256) void vtrans_kernel(
    const unsigned short* __restrict__ Vb, unsigned short* __restrict__ Vtb)
{
    __shared__ unsigned short Ls[64 * PADR];
    const int t0 = blockIdx.x * 64, bh = blockIdx.y;
    const int tid = threadIdx.x;
    #pragma unroll
    for (int it = 0; it < 2; ++it) {
        int r = (tid >> 3) + it * 32, c = (tid & 7) * 8;
        *(bf16x8*)&Ls[r * PADR + c] =
            *(const bf16x8*)&Vb[((size_t)bh * TSEQ + t0 + r) * DKV + c];
    }
    __syncthreads();
    int dv = tid >> 2, tt0 = (tid & 3) * 16;     // dv = j (kv feature), tt0 = t within tile
    unsigned short tmp[16];
    #pragma unroll
    for (int j = 0; j < 16; ++j) tmp[j] = Ls[(tt0 + j) * PADR + dv];
    size_t ob = (((size_t)bh * 32 + (t0 >> 6)) * 64 + dv) * 64 + tt0;
    *(bf16x8*)&Vtb[ob]     = *(bf16x8*)&tmp[0];
    *(bf16x8*)&Vtb[ob + 8] = *(bf16x8*)&tmp[8];
}

// ---------------------------------------------------------------------------
// Kernel 4: causal attention, max-free softmax, den via ones-MFMA.
// SPLIT-K-8 (512 thr): block = pair of 32-row q-tiles (Q, 63-Q), wave w
// takes jt = w mod 8; linear-sum merge in LDS per half. 512 uniform blocks,
// 2/CU, 4 waves/SIMD. V^T now in 64x64 tiles (128B/lane fragment loads).
// XCD-bijective: blockIdx&7 = XCD, 2 bh per XCD (1MB K/V in its L2).
// ---------------------------------------------------------------------------
__global__ __launch_bounds__(512, 4) void attn_kernel(
    const unsigned short* __restrict__ Qb,
    const unsigned short* __restrict__ Kb,
    const unsigned short* __restrict__ Vtb,
    unsigned short* __restrict__ att)
{
    __shared__ __align__(16) char smem[70656];   // merge: Ns[8][32][68]f32|Ds[8][32]; loop: Ps[8][32*72]bf16 aliases
    const int f = blockIdx.x;
    const int xcd = f & 7, idx = f >> 3;         // idx in [0,64)
    const int bh = xcd * 2 + (idx >> 5);
    const int pr = idx & 31;                     // pair index
    const int tid = threadIdx.x, w = tid >> 6, l = tid & 63;
    const int lr = l & 15, g = l >> 4, lk = g * 8;
    const size_t kvb = (size_t)bh * TSEQ * DKV;
    const int bb = bh >> 3, h = bh & 7;

    unsigned short* Psw = (unsigned short*)smem + w * (32 * PADR);
    const short os = (short)0x3F80;              // bf16 1.0
    const bf16x8 ones = {os, os, os, os, os, os, os, os};

    #pragma unroll 1
    for (int half = 0; half < 2; ++half) {
        const int Q = half ? (63 - pr) : pr;
        const int q0 = Q * 32;
        const int ntiles = (Q >> 1) + 1;
        const int last = ntiles - 1;

        bf16x8 qf00 = *(const bf16x8*)&Qb[kvb + (size_t)(q0 +      lr) * DKV + lk];
        bf16x8 qf01 = *(const bf16x8*)&Qb[kvb + (size_t)(q0 +      lr) * DKV + 32 + lk];
        bf16x8 qf10 = *(const bf16x8*)&Qb[kvb + (size_t)(q0 + 16 + lr) * DKV + lk];
        bf16x8 qf11 = *(const bf16x8*)&Qb[kvb + (size_t)(q0 + 16 + lr) * DKV + 32 + lk];

        f32x4 acc0[4] = {}, acc1[4] = {};
        f32x4 dacc0 = {}, dacc1 = {};

        for (int jt = w; jt < ntiles; jt += 8) {
            const unsigned short* Kt = Kb + kvb + (size_t)jt * 64 * DKV;
            const unsigned short* Vt = Vtb + ((size_t)bh * 32 + jt) * 64 * 64;
            #pragma unroll
            for (int c = 0; c < 4; ++c) {
                bf16x8 b0 = *(const bf16x8*)&Kt[(c * 16 + lr) * DKV + lk];
                bf16x8 b1 = *(const bf16x8*)&Kt[(c * 16 + lr) * DKV + 32 + lk];
                f32x4 z0 = {}, z1 = {};
                z0 = MFMA16(qf00, b0, z0); z0 = MFMA16(qf01, b1, z0);
                z1 = MFMA16(qf10, b0, z1); z1 = MFMA16(qf11, b1, z1);
                if (jt == last) {                // causal mask, diagonal tile only
                    int kcol = jt * 64 + c * 16 + lr;
                    #pragma unroll
                    for (int i = 0; i < 4; ++i) {
                        if (kcol > q0 +      g * 4 + i) z0[i] = -64.f;
                        if (kcol > q0 + 16 + g * 4 + i) z1[i] = -64.f;
                    }
                }
                #pragma unroll
                for (int i = 0; i < 4; ++i) {
                    Psw[(     g * 4 + i) * PADR + c * 16 + lr] = f2bf(__expf(z0[i]));
                    Psw[(16 + g * 4 + i) * PADR + c * 16 + lr] = f2bf(__expf(z1[i]));
                }
            }
            bf16x8 pa00 = *(const bf16x8*)&Psw[      lr  * PADR + lk];
            bf16x8 pa01 = *(const bf16x8*)&Psw[      lr  * PADR + 32 + lk];
            bf16x8 pa10 = *(const bf16x8*)&Psw[(16 + lr) * PADR + lk];
            bf16x8 pa11 = *(const bf16x8*)&Psw[(16 + lr) * PADR + 32 + lk];
            #pragma unroll
            for (int n = 0; n < 4; ++n) {
                bf16x8 v0 = *(const bf16x8*)&Vt[(n * 16 + lr) * 64 + lk];
                bf16x8 v1 = *(const bf16x8*)&Vt[(n * 16 + lr) * 64 + 32 + lk];
                acc0[n] = MFMA16(pa00, v0, acc0[n]);
                acc0[n] = MFMA16(pa01, v1, acc0[n]);
                acc1[n] = MFMA16(pa10, v0, acc1[n]);
                acc1[n] = MFMA16(pa11, v1, acc1[n]);
            }
            dacc0 = MFMA16(pa00, ones, dacc0); dacc0 = MFMA16(pa01, ones, dacc0);
            dacc1 = MFMA16(pa10, ones, dacc1); dacc1 = MFMA16(pa11, ones, dacc1);
        }

        // ---- deterministic linear merge of the 8 per-wave partials ----
        __syncthreads();
        float* Ns = (float*)smem;                    // [8][32][68]
        float* Ds = (float*)(smem + 69632);          // [8][32]
        #pragma unroll
        for (int n = 0; n < 4; ++n)
            #pragma unroll
            for (int i = 0; i < 4; ++i) {
                Ns[(size_t)w * (32 * 68) + (     g * 4 + i) * 68 + n * 16 + lr] = acc0[n][i];
                Ns[(size_t)w * (32 * 68) + (16 + g * 4 + i) * 68 + n * 16 + lr] = acc1[n][i];
            }
        if (lr == 0) {
            #pragma unroll
            for (int i = 0; i < 4; ++i) {
                Ds[w * 32 +      g * 4 + i] = dacc0[i];
                Ds[w * 32 + 16 + g * 4 + i] = dacc1[i];
            }
        }
        __syncthreads();

        // 512 threads cover 32 rows x 64 cols, 4 cols/thread
        const int row = tid >> 4, c0 = (tid & 15) * 4;
        float den = 0.f;
        #pragma unroll
        for (int ww = 0; ww < 8; ++ww) den += Ds[ww * 32 + row];
        float inv = 1.0f / den;
        unsigned short o[4];
        #pragma unroll
        for (int j = 0; j < 4; ++j) {
            float s = 0.f;
            #pragma unroll
            for (int ww = 0; ww < 8; ++ww)
                s += Ns[(size_t)ww * (32 * 68) + row * 68 + c0 + j];
            o[j] = f2bf(s * inv);
        }
        *(unsigned long long*)&att[((size_t)bb * TSEQ + q0 + row) * NSEL + h * 64 + c0] =
            *(unsigned long long*)o;
        __syncthreads();   // protect smem before next half reuses Ps
    }
}

// ---------------------------------------------------------------------------
// Kernel 5: output projection  out[4096,1024] = att[4096,512] . Wob[1024,512]^T
// ---------------------------------------------------------------------------
__global__ __launch_bounds__(256) void oproj_gemm(
    const unsigned short* __restrict__ att,
    const unsigned short* __restrict__ Wob,
    float* __restrict__ out)
{
    __shared__ unsigned short As[128 * 64];
    __shared__ unsigned short Bs[128 * 64];
    const int m0 = blockIdx.x * 128, n0 = blockIdx.y * 128;
    const int tid = threadIdx.x, w = tid >> 6, l = tid & 63;
    const int lr = l & 15, g = l >> 4, lk = g * 8;
    const int wr = w >> 1, wc = w & 1;
    const int srow = l >> 3, scol = (l & 7) * 8;

    f32x4 acc[4][4] = {};
    for (int k0 = 0; k0 < NSEL; k0 += 64) {
        __syncthreads();
        #pragma unroll
        for (int i = 0; i < 4; ++i) {
            int chunk = w * 4 + i;
            int row = chunk * 8 + srow;
            g2l16(&att[(size_t)(m0 + row) * NSEL + k0 + scol], &As[chunk * 512]);
            g2l16(&Wob[(size_t)(n0 + row) * NSEL + k0 + scol], &Bs[chunk * 512]);
        }
        __syncthreads();
        #pragma unroll
        for (int kk = 0; kk < 64; kk += 32) {
            bf16x8 a[4], b[4];
            #pragma unroll
            for (int m = 0; m < 4; ++m)
                a[m] = *(const bf16x8*)&As[(wr * 64 + m * 16 + lr) * 64 + kk + lk];
            #pragma unroll
            for (int n = 0; n < 4; ++n)
                b[n] = *(const bf16x8*)&Bs[(wc * 64 + n * 16 + lr) * 64 + kk + lk];
            #pragma unroll
            for (int m = 0; m < 4; ++m)
                #pragma unroll
                for (int n = 0; n < 4; ++n)
                    acc[m][n] = MFMA16(a[m], b[n], acc[m][n]);
        }
    }
    #pragma unroll
    for (int m = 0; m < 4; ++m)
        #pragma unroll
        for (int n = 0; n < 4; ++n)
            #pragma unroll
            for (int i = 0; i < 4; ++i) {
                int row = m0 + wr * 64 + m * 16 + g * 4 + i;
                int col = n0 + wc * 64 + n * 16 + lr;
                out[(size_t)row * DFULL + col] = acc[m][n][i];
            }
}

// ---------------------------------------------------------------------------
extern "C" void kernel_launch(void* const* d_in, const int* in_sizes, int n_in,
                              void* d_out, int out_size, void* d_ws, size_t ws_size,
                              hipStream_t stream) {
    const float* x  = (const float*)d_in[0];
    const float* Wq = (const float*)d_in[1];
    const float* Wk = (const float*)d_in[2];
    const float* Wv = (const float*)d_in[3];
    const float* Wo = (const float*)d_in[4];
    float* out = (float*)d_out;

    char* ws = (char*)d_ws;
    unsigned short* xb  = (unsigned short*)(ws);                    // 8 MB
    unsigned short* Wqb = (unsigned short*)(ws + 8388608);          // 1 MB each,
    unsigned short* Wkb = (unsigned short*)(ws + 9437184);          // contiguous = Wall
    unsigned short* Wvb = (unsigned short*)(ws + 10485760);
    unsigned short* Wob = (unsigned short*)(ws + 11534336);         // 1 MB
    unsigned short* Qb  = (unsigned short*)(ws + 12582912);         // 4 MB
    unsigned short* Kb  = (unsigned short*)(ws + 16777216);         // 4 MB
    unsigned short* Vtb = (unsigned short*)(ws + 20971520);         // 4 MB (tiled)
    unsigned short* Vb  = (unsigned short*)(ws + 25165824);         // 4 MB, dead after
    unsigned short* att = (unsigned short*)(ws + 25165824);         //   vtrans -> reuse

    prep_kernel<<<2048, 256, 0, stream>>>(x, Wq, Wk, Wv, Wo,
                                          xb, Wqb, Wkb, Wvb, Wob, out);
    qkv_gemm<<<dim3(32, 12), 256, 0, stream>>>(xb, Wqb, Qb, Kb, Vb);
    vtrans_kernel<<<dim3(32, 16), 256, 0, stream>>>(Vb, Vtb);
    attn_kernel<<<512, 512, 0, stream>>>(Qb, Kb, Vtb, att);
    oproj_gemm<<<dim3(32, 8), 256, 0, stream>>>(att, Wob, out);
}